// Round 9
// baseline (1431.683 us; speedup 1.0000x reference)
//
#include <hip/hip_runtime.h>

typedef unsigned short u16;
typedef unsigned int u32;

#define L 512
#define BB 512
#define NROWS (L*BB)            // 262144
#define CH (NROWS*64)           // 16777216 elements per output chunk

// f32 weight offsets inside d_ws
enum {
  O_PUW1 = 0,
  O_PUB1 = 1024,
  O_PUW2 = 1088,
  O_PUB2 = 5184,
  O_PXW1 = 5248,
  O_PXB1 = 6272,
  O_PXW2 = 6336,
  O_PXB2 = 10432,
  O_WIH  = 10496,
  O_RNB  = 14592,   // bih + bhh
  O_WHH  = 14656,
  O_AW1  = 18752,   // 64x128
  O_AB1  = 26944,
  O_AW2  = 27008,
  O_AB2  = 31104,
  O_POF1 = 31168,   // 128x128
  O_POF1B= 47552,
  O_POF2 = 47680,
  O_POF2B= 64064,
  O_POMU = 64192,   // 64x128
  O_POMUB= 72384,
  O_POLS = 72448,
  O_POLSB= 80640,
  O_PRF1 = 80704,
  O_PRF1B= 97088,
  O_PRF2 = 97216,
  O_PRF2B= 113600,
  O_PRMU = 113728,
  O_PRMUB= 121920,
  O_FLAG = 121984,  // u32 dtype flag: 1 = bf16 device data, 2 = f32 device data
  O_HB   = 122000   // bf16-packed weight region starts here (u16 units below)
};
// u16 offsets within Wh = (u16*)(W + O_HB)
enum {
  HU1 = 0,       // pu_w1  [64][16]
  HU2 = 1024,    // pu_w2  [64][64]
  HX1 = 5120,    // px_w1  [64][16]
  HX2 = 6144,    // px_w2  [64][64]
  HW3U= 10240,   // rnn_wih [64][64]
  HW3X= 14336,   // a_w1[:,64:] repacked [64][64]
  HEND= 18432
};

__device__ __forceinline__ float b2f(u16 x){ return __uint_as_float(((u32)x)<<16); }
__device__ __forceinline__ u16 f2b(float f){
  u32 u = __float_as_uint(f);
  u32 r = (u + 0x7fffu + ((u>>16)&1u)) >> 16;
  return (u16)r;
}

#if __has_builtin(__builtin_amdgcn_exp2f)
#define EXP2(x) __builtin_amdgcn_exp2f(x)
#else
#define EXP2(x) exp2f(x)
#endif
#if __has_builtin(__builtin_amdgcn_rcpf)
#define RCP(x) __builtin_amdgcn_rcpf(x)
#else
#define RCP(x) (1.0f/(x))
#endif

__device__ __forceinline__ float tanhf_fast(float x){
  float e = EXP2(x * 2.8853900817779268f);
  return 1.0f - 2.0f * RCP(e + 1.0f);
}
__device__ __forceinline__ float sigm_fast(float x){
  float e = EXP2(-1.4426950408889634f * x);
  return RCP(1.0f + e);
}

// Raw workgroup barrier that waits ONLY on LDS ops (lgkmcnt), leaving global
// loads/stores in flight (no vmcnt(0) drain). All cross-barrier data flow in
// the kernels using this is via LDS or registers (register loads are
// auto-waited at first use by the compiler).
__device__ __forceinline__ void bar_lds(){
  __builtin_amdgcn_sched_barrier(0);
  asm volatile("s_waitcnt lgkmcnt(0)" ::: "memory");
  __builtin_amdgcn_s_barrier();
  __builtin_amdgcn_sched_barrier(0);
}

// ---- MFMA types & helpers ----
typedef __attribute__((ext_vector_type(8))) __bf16 bf16x8;
typedef __attribute__((ext_vector_type(4))) float f32x4;

__device__ __forceinline__ f32x4 mfma16(bf16x8 a, bf16x8 b, f32x4 c){
  return __builtin_amdgcn_mfma_f32_16x16x32_bf16(a, b, c, 0, 0, 0);
}
// B-fragment (or A-fragment) from 8 consecutive f32 weights, rounded to bf16
__device__ __forceinline__ bf16x8 wfrag(const float* W, int off){
  union { short s[8]; bf16x8 v; } c;
#pragma unroll
  for (int i=0;i<8;i++) c.s[i] = (short)f2b(W[off+i]);
  return c.v;
}
// 8 packed bf16 from u16 memory (16B aligned)
__device__ __forceinline__ bf16x8 load16(const u16* p){
  union { uint4 u; bf16x8 v; } c;
  c.u = *(const uint4*)p;
  return c.v;
}
__device__ __forceinline__ bf16x8 zfrag(){
  union { uint4 u; bf16x8 v; } c;
  c.u = make_uint4(0,0,0,0);
  return c.v;
}
// A-frag read from a [16][64]-bf16 slot-swizzled LDS tile (8 x 16B slots/row)
__device__ __forceinline__ bf16x8 ldA64(const u32* buf, int r, int s){
  union { uint4 u; bf16x8 v; } c;
  c.u = ((const uint4*)buf)[r*8 + (s ^ (r&7))];
  return c.v;
}
// A-frag read from a [16][128]-bf16 slot-swizzled LDS tile (16 x 16B slots/row)
__device__ __forceinline__ bf16x8 ldT(const u32* buf, int r, int s){
  union { uint4 u; bf16x8 v; } c;
  c.u = ((const uint4*)buf)[r*16 + (s ^ (r&7))];
  return c.v;
}

// ---- MODE-generic load/store helpers (MODE 0: bf16 device data, 1: f32) ----
template<int MODE>
__device__ __forceinline__ float ldOne(const void* p, size_t i){
  if constexpr (MODE) return ((const float*)p)[i];
  else return b2f(((const u16*)p)[i]);
}
template<int MODE>
__device__ __forceinline__ void stOne(void* p, size_t i, float v){
  if constexpr (MODE) ((float*)p)[i] = v;
  else ((u16*)p)[i] = f2b(v);
}
template<int MODE>
__device__ __forceinline__ float wld(const void* p, int i){
  if constexpr (MODE) return ((const float*)p)[i];
  else return b2f(((const u16*)p)[i]);
}
template<int MODE>
__device__ __forceinline__ u16 hld(const void* p, int i){
  if constexpr (MODE) return f2b(((const float*)p)[i]);
  else return ((const u16*)p)[i];
}
template<int MODE>
__device__ __forceinline__ void* chunkp(void* out, int j){
  return (void*)((char*)out + (size_t)j * (size_t)CH * (MODE ? 4 : 2));
}
__device__ __forceinline__ bool live(const float* W, int tag){
  return ((const u32*)W)[O_FLAG] == (u32)tag;
}

// -------------------- probe: classify device dtype --------------------
__global__ void kprobe(const u32* __restrict__ ext, u32* __restrict__ flagp){
  if (threadIdx.x == 0 && blockIdx.x == 0){
    int cnt = 0;
    for (int i = 0; i < 1024; ++i){
      u32 e = (ext[i] >> 7) & 0xFFu;
      cnt += (e >= 110u && e <= 134u) ? 1 : 0;
    }
    flagp[0] = (cnt > 512) ? 1u : 2u;
  }
}

// -------------------- K0: weights -> f32 (+ bf16 packs) in ws --------------------
template<int MODE>
__global__ void k0_convert(
  const void* pu_w1, const void* pu_b1, const void* pu_w2, const void* pu_b2,
  const void* px_w1, const void* px_b1, const void* px_w2, const void* px_b2,
  const void* rnn_wih, const void* rnn_whh, const void* rnn_bih, const void* rnn_bhh,
  const void* a_w1, const void* a_b1, const void* a_w2, const void* a_b2,
  const void* po_f1, const void* po_f1b, const void* po_f2, const void* po_f2b,
  const void* po_mu, const void* po_mub, const void* po_ls, const void* po_lsb,
  const void* pr_f1, const void* pr_f1b, const void* pr_f2, const void* pr_f2b,
  const void* pr_mu, const void* pr_mub,
  float* W)
{
  if (!live(W, MODE ? 2 : 1)) return;
  const int g = blockIdx.x*blockDim.x + threadIdx.x;
  const int gs = gridDim.x*blockDim.x;
#define CVT(off, src, n) for (int i=g;i<(n);i+=gs) W[(off)+i] = wld<MODE>(src,i);
  CVT(O_PUW1, pu_w1, 1024)  CVT(O_PUB1, pu_b1, 64)
  CVT(O_PUW2, pu_w2, 4096)  CVT(O_PUB2, pu_b2, 64)
  CVT(O_PXW1, px_w1, 1024)  CVT(O_PXB1, px_b1, 64)
  CVT(O_PXW2, px_w2, 4096)  CVT(O_PXB2, px_b2, 64)
  CVT(O_WIH,  rnn_wih, 4096)
  CVT(O_WHH,  rnn_whh, 4096)
  CVT(O_AW1,  a_w1, 8192)   CVT(O_AB1, a_b1, 64)
  CVT(O_AW2,  a_w2, 4096)   CVT(O_AB2, a_b2, 64)
  CVT(O_POF1, po_f1, 16384) CVT(O_POF1B, po_f1b, 128)
  CVT(O_POF2, po_f2, 16384) CVT(O_POF2B, po_f2b, 128)
  CVT(O_POMU, po_mu, 8192)  CVT(O_POMUB, po_mub, 64)
  CVT(O_POLS, po_ls, 8192)  CVT(O_POLSB, po_lsb, 64)
  CVT(O_PRF1, pr_f1, 16384) CVT(O_PRF1B, pr_f1b, 128)
  CVT(O_PRF2, pr_f2, 16384) CVT(O_PRF2B, pr_f2b, 128)
  CVT(O_PRMU, pr_mu, 8192)  CVT(O_PRMUB, pr_mub, 64)
#undef CVT
  for (int i=g;i<64;i+=gs) W[O_RNB+i] = wld<MODE>(rnn_bih,i) + wld<MODE>(rnn_bhh,i);

  // bf16-packed weights for k1m (read directly from sources)
  u16* Wh = (u16*)(W + O_HB);
  for (int i=g;i<1024;i+=gs) Wh[HU1+i] = hld<MODE>(pu_w1,i);
  for (int i=g;i<4096;i+=gs) Wh[HU2+i] = hld<MODE>(pu_w2,i);
  for (int i=g;i<1024;i+=gs) Wh[HX1+i] = hld<MODE>(px_w1,i);
  for (int i=g;i<4096;i+=gs) Wh[HX2+i] = hld<MODE>(px_w2,i);
  for (int i=g;i<4096;i+=gs) Wh[HW3U+i] = hld<MODE>(rnn_wih,i);
  for (int i=g;i<4096;i+=gs){
    int j = i>>6, c = i&63;
    Wh[HW3X+i] = hld<MODE>(a_w1, j*128 + 64 + c);
  }
}

// -------------------- K1M: MFMA prep (wave-private tiles, no barriers) --------------------
#define K1_NT 4
template<int MODE>
__global__ __launch_bounds__(512) void k1m(
  const void* __restrict__ ext, const void* __restrict__ obs,
  const float* __restrict__ W, void* __restrict__ outb)
{
  if (!live(W, MODE ? 2 : 1)) return;
  void* rnn_in = chunkp<MODE>(outb, 1);
  void* ax_out = chunkp<MODE>(outb, 2);

  const int tid = threadIdx.x;
  const int wave = tid>>6, lane = tid&63;
  const int lr = lane&15, lg = lane>>4;
  const u16* Wh = (const u16*)(W + O_HB);

  __shared__ __align__(16) u16 Et[8][1024];   // wave-private [16][64] bf16, slot-swizzled
  u16* myT = Et[wave];
  u32* myT32 = (u32*)myT;

#pragma unroll 1
  for (int p=0;p<2;p++){
    const void* src = p ? obs : ext;
    void* dst = p ? ax_out : rnn_in;
    const int h1 = p?HX1:HU1, h2 = p?HX2:HU2, h3 = p?HW3X:HW3U;
    const int b1o = p?O_PXB1:O_PUB1, b2o = p?O_PXB2:O_PUB2, b3o = p?O_AB1:O_RNB;

    // ---- weight fragments ----
    bf16x8 w1[4], w2[4][2], w3[4][2];
    float bb1[4], bb2[4], bb3[4];
#pragma unroll
    for (int n=0;n<4;n++){
      const int j = n*16 + lr;
      w1[n] = (lg<2) ? load16(Wh + h1 + j*16 + lg*8) : zfrag();
#pragma unroll
      for (int kk=0;kk<2;kk++){
        w2[n][kk] = load16(Wh + h2 + j*64 + kk*32 + lg*8);
        w3[n][kk] = load16(Wh + h3 + j*64 + kk*32 + lg*8);
      }
      bb1[n] = W[b1o+j]; bb2[n] = W[b2o+j]; bb3[n] = W[b3o+j];
    }

#pragma unroll 1
    for (int it=0; it<K1_NT; ++it){
      const size_t row0 = ((size_t)(blockIdx.x*8 + wave)*K1_NT + it)*16;

      // ---- input A-frag (K=16 padded to 32) ----
      bf16x8 xa;
      if (lg < 2){
        if constexpr (MODE){
          const float4* sp = (const float4*)((const float*)src + (row0+lr)*16);
          float4 f0 = sp[lg*2], f1 = sp[lg*2+1];
          union { short s[8]; bf16x8 v; } c;
          c.s[0]=(short)f2b(f0.x); c.s[1]=(short)f2b(f0.y);
          c.s[2]=(short)f2b(f0.z); c.s[3]=(short)f2b(f0.w);
          c.s[4]=(short)f2b(f1.x); c.s[5]=(short)f2b(f1.y);
          c.s[6]=(short)f2b(f1.z); c.s[7]=(short)f2b(f1.w);
          xa = c.v;
        } else {
          xa = load16((const u16*)src + (row0+lr)*16 + lg*8);
        }
      } else xa = zfrag();

      // ---- L1 ----
      f32x4 c[4];
#pragma unroll
      for (int n=0;n<4;n++){
        f32x4 ci = {bb1[n],bb1[n],bb1[n],bb1[n]};
        ci = mfma16(xa, w1[n], ci);
#pragma unroll
        for (int r=0;r<4;r++){
          float v = fmaxf(ci[r], 0.0f);
          const int b = lg*4 + r, j = n*16 + lr;
          myT[b*64 + (((j>>3)^(b&7))<<3) + (j&7)] = f2b(v);
        }
      }
      // ---- L2 ----
      {
        bf16x8 a0 = ldA64(myT32, lr, lg);
        bf16x8 a1 = ldA64(myT32, lr, 4+lg);
#pragma unroll
        for (int n=0;n<4;n++){
          f32x4 ci = {bb2[n],bb2[n],bb2[n],bb2[n]};
          ci = mfma16(a0, w2[n][0], ci);
          ci = mfma16(a1, w2[n][1], ci);
          c[n] = ci;
        }
#pragma unroll
        for (int n=0;n<4;n++)
#pragma unroll
          for (int r=0;r<4;r++){
            float v = fmaxf(c[n][r], 0.0f);
            const int b = lg*4 + r, j = n*16 + lr;
            myT[b*64 + (((j>>3)^(b&7))<<3) + (j&7)] = f2b(v);
          }
      }
      // ---- L3 (linear) ----
      {
        bf16x8 a0 = ldA64(myT32, lr, lg);
        bf16x8 a1 = ldA64(myT32, lr, 4+lg);
#pragma unroll
        for (int n=0;n<4;n++){
          f32x4 ci = {bb3[n],bb3[n],bb3[n],bb3[n]};
          ci = mfma16(a0, w3[n][0], ci);
          ci = mfma16(a1, w3[n][1], ci);
          c[n] = ci;
        }
#pragma unroll
        for (int n=0;n<4;n++)
#pragma unroll
          for (int r=0;r<4;r++){
            const int b = lg*4 + r, j = n*16 + lr;
            myT[b*64 + (((j>>3)^(b&7))<<3) + (j&7)] = f2b(c[n][r]);
          }
      }
      // ---- coalesced store: 2 slots per lane ----
#pragma unroll
      for (int s2=0;s2<2;s2++){
        const int s_lin = lane*2 + s2;
        const int r = s_lin>>3, sl = s_lin&7;
        uint4 v = ((const uint4*)myT32)[r*8 + (sl^(r&7))];
        if constexpr (MODE){
          float* dp = (float*)dst + (row0+r)*64 + sl*8;
          u32 w[4] = {v.x, v.y, v.z, v.w};
          float f[8];
#pragma unroll
          for (int i=0;i<4;i++){ f[2*i] = b2f((u16)(w[i]&0xffffu)); f[2*i+1] = b2f((u16)(w[i]>>16)); }
          ((float4*)dp)[0] = make_float4(f[0],f[1],f[2],f[3]);
          ((float4*)dp)[1] = make_float4(f[4],f[5],f[6],f[7]);
        } else {
          ((uint4*)((u16*)dst + (row0+r)*64))[sl] = v;
        }
      }
    }
  }
}

// 16-term partial dot with 2 accumulator chains
__device__ __forceinline__ float dot16(const float* w, float4 a, float4 b, float4 c, float4 d){
  float s0=0.f, s1=0.f;
  s0=fmaf(w[0],a.x,s0);  s1=fmaf(w[1],a.y,s1);  s0=fmaf(w[2],a.z,s0);  s1=fmaf(w[3],a.w,s1);
  s0=fmaf(w[4],b.x,s0);  s1=fmaf(w[5],b.y,s1);  s0=fmaf(w[6],b.z,s0);  s1=fmaf(w[7],b.w,s1);
  s0=fmaf(w[8],c.x,s0);  s1=fmaf(w[9],c.y,s1);  s0=fmaf(w[10],c.z,s0); s1=fmaf(w[11],c.w,s1);
  s0=fmaf(w[12],d.x,s0); s1=fmaf(w[13],d.y,s1); s0=fmaf(w[14],d.z,s0); s1=fmaf(w[15],d.w,s1);
  return s0+s1;
}

// -------------------- K2: sequential RNN + a-layer (WG per batch lane) --------------------
// r4 structure + lgkm-only barriers + REGISTER PREFETCH of rnn_in/ax one step
// ahead (loads issued after consumption, stay in flight across the barriers).
template<int MODE>
__global__ __launch_bounds__(256) void k2_rnn(
  const float* __restrict__ W, void* __restrict__ outb)
{
  if (!live(W, MODE ? 2 : 1)) return;
  void* a_seq  = chunkp<MODE>(outb, 0);
  void* rnn_in = chunkp<MODE>(outb, 1);
  void* ax     = chunkp<MODE>(outb, 2);
  void* d_seq  = chunkp<MODE>(outb, 3);

  const int b = blockIdx.x;
  const int tid = threadIdx.x;
  const int q = tid>>6, j = tid&63;

  float wh[16], wa1[16], wa2[16];
#pragma unroll
  for (int i=0;i<16;i++){
    wh[i]  = W[O_WHH + j*64  + q*16 + i];
    wa1[i] = W[O_AW1 + j*128 + q*16 + i];   // d-half (cols 0..63)
    wa2[i] = W[O_AW2 + j*64  + q*16 + i];
  }
  const float ab2j = W[O_AB2 + j];

  __shared__ __align__(16) float h_lds[64];
  __shared__ __align__(16) float v_lds[64];
  __shared__ __align__(16) float red1[256], red2[256], red3[256];
  if (tid < 64){ h_lds[tid] = 0.f; v_lds[tid] = 0.f; }

  const size_t brow = (size_t)b*64 + j;
  float pre = 0.f;
  if (q==0) pre = ldOne<MODE>(rnn_in, brow);   // rnn_in[t=0]
  __syncthreads();

  for (int t=0; t<L+2; ++t){
    const float4* hv = (const float4*)(&h_lds[q*16]);
    const float4* vv = (const float4*)(&v_lds[q*16]);
    float4 h0=hv[0], h1=hv[1], h2=hv[2], h3=hv[3];
    float4 v0=vv[0], v1=vv[1], v2=vv[2], v3=vv[3];
    red1[tid] = dot16(wh,  h0,h1,h2,h3);
    red2[tid] = dot16(wa1, h0,h1,h2,h3);
    red3[tid] = dot16(wa2, v0,v1,v2,v3);
    bar_lds();
    if (q==0){
      if (t < L){
        const size_t idx = (size_t)t*(BB*64) + brow;
        float s = red1[j]+red1[64+j]+red1[128+j]+red1[192+j] + pre;
        float hn = tanhf_fast(s);
        h_lds[j] = hn;
        stOne<MODE>(d_seq, idx, hn);
      }
      if (t+1 < L) pre = ldOne<MODE>(rnn_in, (size_t)(t+1)*(BB*64) + brow);
    } else if (q==1){
      if (t>=1 && t<=L){
        const size_t idx = (size_t)(t-1)*(BB*64) + brow;
        float s = red2[j]+red2[64+j]+red2[128+j]+red2[192+j] + pre;
        v_lds[j] = tanhf_fast(s);
      }
      if (t < L) pre = ldOne<MODE>(ax, (size_t)t*(BB*64) + brow);  // used at t+1
    } else if (q==2){
      if (t>=2){
        const size_t idx = (size_t)(t-2)*(BB*64) + brow;
        float s = red3[j]+red3[64+j]+red3[128+j]+red3[192+j] + ab2j;
        stOne<MODE>(a_seq, idx, s);
      }
    }
    bar_lds();
  }
}

// -------------------- K4M: MFMA latent scan, 2 barriers/step --------------------
// Phase A: all 8 waves DBlock fc1/fc2 -> T; all 512 threads store step t-1
//          outputs (coalesced, from LDS staging); waves 6,7 issue t+1 prefetch.
// Phase B: waves 0-3 own j-quadrant, compute po_mu+po_ls+pr_mu (12 MFMA) and
//          the full z update IN REGISTERS; write z->Zbuf + outputs->staging.
//          Waves 6,7 write prefetched a/d/eps into LDS.
template<int MODE>
__global__ __launch_bounds__(512,2) void k4m(
  const float* __restrict__ W,
  const void* __restrict__ noise, void* __restrict__ outb)
{
  if (!live(W, MODE ? 2 : 1)) return;
  void* amu = chunkp<MODE>(outb, 0);   // reads a_seq, writes state_mu
  void* lsc = chunkp<MODE>(outb, 1);   // writes state_logsigma
  void* zc  = chunkp<MODE>(outb, 2);   // writes sampled_state
  void* dsq = chunkp<MODE>(outb, 3);   // reads d_seq

  const int G = blockIdx.x;
  const int tid = threadIdx.x;
  const int wave = tid>>6, lane = tid&63;
  const int lr = lane&15, lg = lane>>4;

  __shared__ __align__(16) u32 Zbuf[512];          // [16][64] bf16, 16B-slot swizzled
  __shared__ __align__(16) u32 Abuf[2][512];       // a_t
  __shared__ __align__(16) u32 Dbuf[2][512];       // d_t
  __shared__ __align__(16) u32 Ebuf[2][1024];      // eps as f32 bits, [16][64]
  __shared__ __align__(16) u32 Tpo[1024];          // [16][128] bf16 swizzled
  __shared__ __align__(16) u32 Tpr[1024];
  __shared__ __align__(16) u16 Smu[1024];          // staging [16][64] bf16, plain
  __shared__ __align__(16) u16 Sls[1024];
  __shared__ __align__(16) u16 Sz[1024];

  const bool isPo = wave < 4;
  const int wq = wave & 3;
  const int jA = wq*32;
  const int j2 = wq*16 + lr;

  // ---- stage-A weight fragments (all 8 waves) ----
  const int of1 = isPo ? O_POF1 : O_PRF1;
  const int of2 = isPo ? O_POF2 : O_PRF2;
  bf16x8 wf1[2][4], wf2[2][4];
  float bA1[2], bA2[2];
#pragma unroll
  for (int nt=0; nt<2; ++nt){
    const int j = jA + nt*16 + lr;
    bA1[nt] = W[(isPo?O_POF1B:O_PRF1B) + j];
    bA2[nt] = W[(isPo?O_POF2B:O_PRF2B) + j];
#pragma unroll
    for (int kk=0; kk<4; ++kk){
      const int k = kk*32 + lg*8;
      wf1[nt][kk] = wfrag(W, of1 + j*128 + k);
      wf2[nt][kk] = wfrag(W, of2 + j*128 + k);
    }
  }
  // ---- phase-B weight fragments (waves 0..3): all 3 output mats for quadrant ----
  bf16x8 wmu[4], wls[4], wpr[4];
  float bm = 0.f, bl = 0.f;
  if (wave < 4){
#pragma unroll
    for (int kk=0; kk<4; ++kk){
      const int k = kk*32 + lg*8;
      wmu[kk] = wfrag(W, O_POMU + j2*128 + k);
      wls[kk] = wfrag(W, O_POLS + j2*128 + k);
      wpr[kk] = wfrag(W, O_PRMU + j2*128 + k);
    }
    bm = W[O_POMUB + j2] + W[O_PRMUB + j2];
    bl = W[O_POLSB + j2];
  }

  Zbuf[tid & 511] = 0;

  // ---- prefetch machinery (waves 6,7; wave 6 also eps) ----
  const int pr_ = lane>>2, pc = lane&3;
  float4 pA[4], pE[4]; uint4 qA[2], qE[2];

  auto pf_issue = [&](int tt){
    const size_t rowb = ((size_t)tt*BB + G*16 + pr_)*64;
    const void* gsrc = (wave==6) ? amu : dsq;
    if constexpr (MODE){
      const float4* sp = (const float4*)((const float*)gsrc + rowb) + pc*4;
#pragma unroll
      for (int i=0;i<4;i++) pA[i] = sp[i];
      if (wave==6){
        const float4* ep = (const float4*)((const float*)noise + rowb) + pc*4;
#pragma unroll
        for (int i=0;i<4;i++) pE[i] = ep[i];
      }
    } else {
      const uint4* sp = (const uint4*)((const u16*)gsrc + rowb) + pc*2;
      qA[0] = sp[0]; qA[1] = sp[1];
      if (wave==6){
        const uint4* ep = (const uint4*)((const u16*)noise + rowb) + pc*2;
        qE[0] = ep[0]; qE[1] = ep[1];
      }
    }
  };
  auto pf_write = [&](int buf){
    u32* dst = (wave==6) ? Abuf[buf] : Dbuf[buf];
    uint4* d0 = (uint4*)dst + (pr_*8 + ((pc*2  ) ^ (pr_&7)));
    uint4* d1 = (uint4*)dst + (pr_*8 + ((pc*2+1) ^ (pr_&7)));
    if constexpr (MODE){
      u32 w[8];
#pragma unroll
      for (int i=0;i<4;i++){
        w[2*i]   = (u32)f2b(pA[i].x) | ((u32)f2b(pA[i].y)<<16);
        w[2*i+1] = (u32)f2b(pA[i].z) | ((u32)f2b(pA[i].w)<<16);
      }
      *d0 = make_uint4(w[0],w[1],w[2],w[3]);
      *d1 = make_uint4(w[4],w[5],w[6],w[7]);
      if (wave==6){
        uint4* eb = (uint4*)Ebuf[buf] + (pr_*16 + pc*4);
#pragma unroll
        for (int i=0;i<4;i++){
          union { float4 f; uint4 u; } cv; cv.f = pE[i];
          eb[i] = cv.u;
        }
      }
    } else {
      *d0 = qA[0]; *d1 = qA[1];
      if (wave==6){
        u32* Eb = Ebuf[buf] + pr_*64 + pc*16;
        u32 ww[4] = {qE[0].x, qE[0].y, qE[0].z, qE[0].w};
#pragma unroll
        for (int i=0;i<4;i++){ Eb[2*i] = ww[i]<<16; Eb[2*i+1] = ww[i] & 0xffff0000u; }
        u32 w2[4] = {qE[1].x, qE[1].y, qE[1].z, qE[1].w};
#pragma unroll
        for (int i=0;i<4;i++){ Eb[8+2*i] = w2[i]<<16; Eb[8+2*i+1] = w2[i] & 0xffff0000u; }
      }
    }
  };

  if (wave >= 6){ pf_issue(0); pf_write(0); }
  __syncthreads();

#pragma unroll 1
  for (int t=0; t<=L; ++t){
    // ================= phase A =================
    if (wave >= 6 && t+1 < L) pf_issue(t+1);

    // store step t-1 outputs from staging (coalesced, all 512 threads)
    if (t > 0){
      const int sb = tid>>5, sj = (tid&31)*2;
      const int si = sb*32 + (sj>>1);
      u32 wm = ((const u32*)Smu)[si];
      u32 wl = ((const u32*)Sls)[si];
      u32 wz = ((const u32*)Sz)[si];
      const size_t idx = ((size_t)(t-1)*BB + G*16 + sb)*64 + sj;
      if constexpr (MODE){
        *(float2*)((float*)amu + idx) = make_float2(b2f((u16)(wm&0xffffu)), b2f((u16)(wm>>16)));
        *(float2*)((float*)lsc + idx) = make_float2(b2f((u16)(wl&0xffffu)), b2f((u16)(wl>>16)));
        *(float2*)((float*)zc  + idx) = make_float2(b2f((u16)(wz&0xffffu)), b2f((u16)(wz>>16)));
      } else {
        *(u32*)((u16*)amu + idx) = wm;
        *(u32*)((u16*)lsc + idx) = wl;
        *(u32*)((u16*)zc  + idx) = wz;
      }
    }

    if (t < L){
      const u32* ADc = isPo ? Abuf[t&1] : Dbuf[t&1];
      bf16x8 a0 = ldA64(Zbuf, lr, lg);
      bf16x8 a1 = ldA64(Zbuf, lr, 4+lg);
      bf16x8 a2 = ldA64(ADc,  lr, lg);
      bf16x8 a3 = ldA64(ADc,  lr, 4+lg);
      f32x4 c1[2], c2[2];
#pragma unroll
      for (int nt=0; nt<2; ++nt){
        f32x4 i1 = {bA1[nt],bA1[nt],bA1[nt],bA1[nt]};
        f32x4 i2 = {bA2[nt],bA2[nt],bA2[nt],bA2[nt]};
        i1 = mfma16(a0, wf1[nt][0], i1);
        i1 = mfma16(a1, wf1[nt][1], i1);
        i1 = mfma16(a2, wf1[nt][2], i1);
        i1 = mfma16(a3, wf1[nt][3], i1);
        i2 = mfma16(a0, wf2[nt][0], i2);
        i2 = mfma16(a1, wf2[nt][1], i2);
        i2 = mfma16(a2, wf2[nt][2], i2);
        i2 = mfma16(a3, wf2[nt][3], i2);
        c1[nt] = i1; c2[nt] = i2;
      }
      u16* Td = (u16*)(isPo ? Tpo : Tpr);
#pragma unroll
      for (int nt=0; nt<2; ++nt)
#pragma unroll
        for (int r=0; r<4; ++r){
          float tv = tanhf_fast(c1[nt][r]) * sigm_fast(c2[nt][r]);
          const int j = jA + nt*16 + lr;
          const int bb = lg*4 + r;
          Td[bb*128 + (((j>>3)^(bb&7))<<3) + (j&7)] = f2b(tv);
        }
    }
    bar_lds();  // S2: T ready; staging consumed

    // ================= phase B =================
    if (t < L){
      if (wave < 4){
        bf16x8 tp0 = ldT(Tpo, lr, 0+lg), tp1 = ldT(Tpo, lr, 4+lg);
        bf16x8 tp2 = ldT(Tpo, lr, 8+lg), tp3 = ldT(Tpo, lr, 12+lg);
        bf16x8 tr0 = ldT(Tpr, lr, 0+lg), tr1 = ldT(Tpr, lr, 4+lg);
        bf16x8 tr2 = ldT(Tpr, lr, 8+lg), tr3 = ldT(Tpr, lr, 12+lg);
        f32x4 cmu = {bm,bm,bm,bm};
        f32x4 cls = {bl,bl,bl,bl};
        f32x4 cpr = {0.f,0.f,0.f,0.f};
        cmu = mfma16(tp0, wmu[0], cmu);
        cmu = mfma16(tp1, wmu[1], cmu);
        cmu = mfma16(tp2, wmu[2], cmu);
        cmu = mfma16(tp3, wmu[3], cmu);
        cls = mfma16(tp0, wls[0], cls);
        cls = mfma16(tp1, wls[1], cls);
        cls = mfma16(tp2, wls[2], cls);
        cls = mfma16(tp3, wls[3], cls);
        cpr = mfma16(tr0, wpr[0], cpr);
        cpr = mfma16(tr1, wpr[1], cpr);
        cpr = mfma16(tr2, wpr[2], cpr);
        cpr = mfma16(tr3, wpr[3], cpr);
#pragma unroll
        for (int r=0; r<4; ++r){
          const int bb = lg*4 + r;
          float mu = cmu[r] + cpr[r];
          float ls = cls[r];
          float eps = __uint_as_float(Ebuf[t&1][bb*64 + j2]);
          float z = fmaf(EXP2(ls*0.7213475204444817f), eps, mu);
          ((u16*)Zbuf)[(bb*8 + ((j2>>3)^(bb&7)))*8 + (j2&7)] = f2b(z);
          Smu[bb*64 + j2] = f2b(mu);
          Sls[bb*64 + j2] = f2b(ls);
          Sz [bb*64 + j2] = f2b(z);
        }
      } else if (wave >= 6 && t+1 < L){
        pf_write((t+1)&1);
      }
    }
    bar_lds();  // S3: z + staging + next a/d/eps ready
  }
}

extern "C" void kernel_launch(void* const* d_in, const int* in_sizes, int n_in,
                              void* d_out, int out_size, void* d_ws, size_t ws_size,
                              hipStream_t stream)
{
  (void)in_sizes; (void)n_in; (void)out_size; (void)ws_size;

  const void* ext   = d_in[0];
  const void* obs   = d_in[1];
  const void* noise = d_in[2];
  float* W = (float*)d_ws;

  kprobe<<<1,64,0,stream>>>((const u32*)ext, (u32*)W + O_FLAG);

#define K0ARGS \
    d_in[3],  d_in[4],  d_in[5],  d_in[6],  d_in[7],  d_in[8],  d_in[9],  d_in[10], \
    d_in[11], d_in[12], d_in[13], d_in[14], d_in[15], d_in[16], d_in[17], d_in[18], \
    d_in[19], d_in[20], d_in[21], d_in[22], d_in[23], d_in[24], d_in[25], d_in[26], \
    d_in[27], d_in[28], d_in[29], d_in[30], d_in[31], d_in[32], W

  k0_convert<0><<<64,256,0,stream>>>(K0ARGS);
  k0_convert<1><<<64,256,0,stream>>>(K0ARGS);
#undef K0ARGS

  k1m<0><<<NROWS/(8*K1_NT*16), 512, 0, stream>>>(ext, obs, W, d_out);
  k1m<1><<<NROWS/(8*K1_NT*16), 512, 0, stream>>>(ext, obs, W, d_out);

  k2_rnn<0><<<BB, 256, 0, stream>>>(W, d_out);
  k2_rnn<1><<<BB, 256, 0, stream>>>(W, d_out);

  k4m<0><<<32, 512, 0, stream>>>(W, noise, d_out);
  k4m<1><<<32, 512, 0, stream>>>(W, noise, d_out);
}

// Round 10
// 1018.720 us; speedup vs baseline: 1.4054x; 1.4054x over previous
//
#include <hip/hip_runtime.h>

typedef unsigned short u16;
typedef unsigned int u32;

#define L 512
#define BB 512
#define NROWS (L*BB)            // 262144
#define CH (NROWS*64)           // 16777216 elements per output chunk

// f32 weight offsets inside d_ws
enum {
  O_PUW1 = 0,
  O_PUB1 = 1024,
  O_PUW2 = 1088,
  O_PUB2 = 5184,
  O_PXW1 = 5248,
  O_PXB1 = 6272,
  O_PXW2 = 6336,
  O_PXB2 = 10432,
  O_WIH  = 10496,
  O_RNB  = 14592,   // bih + bhh
  O_WHH  = 14656,
  O_AW1  = 18752,   // 64x128
  O_AB1  = 26944,
  O_AW2  = 27008,
  O_AB2  = 31104,
  O_POF1 = 31168,   // 128x128
  O_POF1B= 47552,
  O_POF2 = 47680,
  O_POF2B= 64064,
  O_POMU = 64192,   // 64x128
  O_POMUB= 72384,
  O_POLS = 72448,
  O_POLSB= 80640,
  O_PRF1 = 80704,
  O_PRF1B= 97088,
  O_PRF2 = 97216,
  O_PRF2B= 113600,
  O_PRMU = 113728,
  O_PRMUB= 121920,
  O_FLAG = 121984,  // u32 dtype flag: 1 = bf16 device data, 2 = f32 device data
  O_HB   = 122000   // bf16-packed weight region starts here (u16 units below)
};
// u16 offsets within Wh = (u16*)(W + O_HB)
enum {
  HU1 = 0,       // pu_w1  [64][16]
  HU2 = 1024,    // pu_w2  [64][64]
  HX1 = 5120,    // px_w1  [64][16]
  HX2 = 6144,    // px_w2  [64][64]
  HW3U= 10240,   // rnn_wih [64][64]
  HW3X= 14336,   // a_w1[:,64:] repacked [64][64]
  HEND= 18432
};

__device__ __forceinline__ float b2f(u16 x){ return __uint_as_float(((u32)x)<<16); }
__device__ __forceinline__ u16 f2b(float f){
  u32 u = __float_as_uint(f);
  u32 r = (u + 0x7fffu + ((u>>16)&1u)) >> 16;
  return (u16)r;
}

#if __has_builtin(__builtin_amdgcn_exp2f)
#define EXP2(x) __builtin_amdgcn_exp2f(x)
#else
#define EXP2(x) exp2f(x)
#endif
#if __has_builtin(__builtin_amdgcn_rcpf)
#define RCP(x) __builtin_amdgcn_rcpf(x)
#else
#define RCP(x) (1.0f/(x))
#endif

__device__ __forceinline__ float tanhf_fast(float x){
  float e = EXP2(x * 2.8853900817779268f);
  return 1.0f - 2.0f * RCP(e + 1.0f);
}
__device__ __forceinline__ float sigm_fast(float x){
  float e = EXP2(-1.4426950408889634f * x);
  return RCP(1.0f + e);
}

// Raw workgroup barrier that waits ONLY on LDS ops (lgkmcnt), leaving global
// loads/stores in flight (no vmcnt(0) drain). All cross-barrier data flow in
// the kernels using this is via LDS or registers (register loads are
// auto-waited at first use by the compiler).
__device__ __forceinline__ void bar_lds(){
  __builtin_amdgcn_sched_barrier(0);
  asm volatile("s_waitcnt lgkmcnt(0)" ::: "memory");
  __builtin_amdgcn_s_barrier();
  __builtin_amdgcn_sched_barrier(0);
}

// ---- MFMA types & helpers ----
typedef __attribute__((ext_vector_type(8))) __bf16 bf16x8;
typedef __attribute__((ext_vector_type(4))) float f32x4;

__device__ __forceinline__ f32x4 mfma16(bf16x8 a, bf16x8 b, f32x4 c){
  return __builtin_amdgcn_mfma_f32_16x16x32_bf16(a, b, c, 0, 0, 0);
}
// B-fragment (or A-fragment) from 8 consecutive f32 weights, rounded to bf16
__device__ __forceinline__ bf16x8 wfrag(const float* W, int off){
  union { short s[8]; bf16x8 v; } c;
#pragma unroll
  for (int i=0;i<8;i++) c.s[i] = (short)f2b(W[off+i]);
  return c.v;
}
// 8 packed bf16 from u16 memory (16B aligned)
__device__ __forceinline__ bf16x8 load16(const u16* p){
  union { uint4 u; bf16x8 v; } c;
  c.u = *(const uint4*)p;
  return c.v;
}
__device__ __forceinline__ bf16x8 zfrag(){
  union { uint4 u; bf16x8 v; } c;
  c.u = make_uint4(0,0,0,0);
  return c.v;
}
// A-frag read from a [16][64]-bf16 slot-swizzled LDS tile (8 x 16B slots/row)
__device__ __forceinline__ bf16x8 ldA64(const u32* buf, int r, int s){
  union { uint4 u; bf16x8 v; } c;
  c.u = ((const uint4*)buf)[r*8 + (s ^ (r&7))];
  return c.v;
}
// A-frag read from a [16][128]-bf16 slot-swizzled LDS tile (16 x 16B slots/row)
__device__ __forceinline__ bf16x8 ldT(const u32* buf, int r, int s){
  union { uint4 u; bf16x8 v; } c;
  c.u = ((const uint4*)buf)[r*16 + (s ^ (r&7))];
  return c.v;
}

// ---- MODE-generic load/store helpers (MODE 0: bf16 device data, 1: f32) ----
template<int MODE>
__device__ __forceinline__ float ldOne(const void* p, size_t i){
  if constexpr (MODE) return ((const float*)p)[i];
  else return b2f(((const u16*)p)[i]);
}
template<int MODE>
__device__ __forceinline__ void stOne(void* p, size_t i, float v){
  if constexpr (MODE) ((float*)p)[i] = v;
  else ((u16*)p)[i] = f2b(v);
}
template<int MODE>
__device__ __forceinline__ float wld(const void* p, int i){
  if constexpr (MODE) return ((const float*)p)[i];
  else return b2f(((const u16*)p)[i]);
}
template<int MODE>
__device__ __forceinline__ u16 hld(const void* p, int i){
  if constexpr (MODE) return f2b(((const float*)p)[i]);
  else return ((const u16*)p)[i];
}
template<int MODE>
__device__ __forceinline__ void* chunkp(void* out, int j){
  return (void*)((char*)out + (size_t)j * (size_t)CH * (MODE ? 4 : 2));
}
__device__ __forceinline__ bool live(const float* W, int tag){
  return ((const u32*)W)[O_FLAG] == (u32)tag;
}

// -------------------- probe: classify device dtype --------------------
__global__ void kprobe(const u32* __restrict__ ext, u32* __restrict__ flagp){
  if (threadIdx.x == 0 && blockIdx.x == 0){
    int cnt = 0;
    for (int i = 0; i < 1024; ++i){
      u32 e = (ext[i] >> 7) & 0xFFu;
      cnt += (e >= 110u && e <= 134u) ? 1 : 0;
    }
    flagp[0] = (cnt > 512) ? 1u : 2u;
  }
}

// -------------------- K0: weights -> f32 (+ bf16 packs) in ws --------------------
template<int MODE>
__global__ void k0_convert(
  const void* pu_w1, const void* pu_b1, const void* pu_w2, const void* pu_b2,
  const void* px_w1, const void* px_b1, const void* px_w2, const void* px_b2,
  const void* rnn_wih, const void* rnn_whh, const void* rnn_bih, const void* rnn_bhh,
  const void* a_w1, const void* a_b1, const void* a_w2, const void* a_b2,
  const void* po_f1, const void* po_f1b, const void* po_f2, const void* po_f2b,
  const void* po_mu, const void* po_mub, const void* po_ls, const void* po_lsb,
  const void* pr_f1, const void* pr_f1b, const void* pr_f2, const void* pr_f2b,
  const void* pr_mu, const void* pr_mub,
  float* W)
{
  if (!live(W, MODE ? 2 : 1)) return;
  const int g = blockIdx.x*blockDim.x + threadIdx.x;
  const int gs = gridDim.x*blockDim.x;
#define CVT(off, src, n) for (int i=g;i<(n);i+=gs) W[(off)+i] = wld<MODE>(src,i);
  CVT(O_PUW1, pu_w1, 1024)  CVT(O_PUB1, pu_b1, 64)
  CVT(O_PUW2, pu_w2, 4096)  CVT(O_PUB2, pu_b2, 64)
  CVT(O_PXW1, px_w1, 1024)  CVT(O_PXB1, px_b1, 64)
  CVT(O_PXW2, px_w2, 4096)  CVT(O_PXB2, px_b2, 64)
  CVT(O_WIH,  rnn_wih, 4096)
  CVT(O_WHH,  rnn_whh, 4096)
  CVT(O_AW1,  a_w1, 8192)   CVT(O_AB1, a_b1, 64)
  CVT(O_AW2,  a_w2, 4096)   CVT(O_AB2, a_b2, 64)
  CVT(O_POF1, po_f1, 16384) CVT(O_POF1B, po_f1b, 128)
  CVT(O_POF2, po_f2, 16384) CVT(O_POF2B, po_f2b, 128)
  CVT(O_POMU, po_mu, 8192)  CVT(O_POMUB, po_mub, 64)
  CVT(O_POLS, po_ls, 8192)  CVT(O_POLSB, po_lsb, 64)
  CVT(O_PRF1, pr_f1, 16384) CVT(O_PRF1B, pr_f1b, 128)
  CVT(O_PRF2, pr_f2, 16384) CVT(O_PRF2B, pr_f2b, 128)
  CVT(O_PRMU, pr_mu, 8192)  CVT(O_PRMUB, pr_mub, 64)
#undef CVT
  for (int i=g;i<64;i+=gs) W[O_RNB+i] = wld<MODE>(rnn_bih,i) + wld<MODE>(rnn_bhh,i);

  // bf16-packed weights for k1m (read directly from sources)
  u16* Wh = (u16*)(W + O_HB);
  for (int i=g;i<1024;i+=gs) Wh[HU1+i] = hld<MODE>(pu_w1,i);
  for (int i=g;i<4096;i+=gs) Wh[HU2+i] = hld<MODE>(pu_w2,i);
  for (int i=g;i<1024;i+=gs) Wh[HX1+i] = hld<MODE>(px_w1,i);
  for (int i=g;i<4096;i+=gs) Wh[HX2+i] = hld<MODE>(px_w2,i);
  for (int i=g;i<4096;i+=gs) Wh[HW3U+i] = hld<MODE>(rnn_wih,i);
  for (int i=g;i<4096;i+=gs){
    int j = i>>6, c = i&63;
    Wh[HW3X+i] = hld<MODE>(a_w1, j*128 + 64 + c);
  }
}

// -------------------- K1M: MFMA prep (wave-private tiles, no barriers) --------------------
#define K1_NT 4
template<int MODE>
__global__ __launch_bounds__(512) void k1m(
  const void* __restrict__ ext, const void* __restrict__ obs,
  const float* __restrict__ W, void* __restrict__ outb)
{
  if (!live(W, MODE ? 2 : 1)) return;
  void* rnn_in = chunkp<MODE>(outb, 1);
  void* ax_out = chunkp<MODE>(outb, 2);

  const int tid = threadIdx.x;
  const int wave = tid>>6, lane = tid&63;
  const int lr = lane&15, lg = lane>>4;
  const u16* Wh = (const u16*)(W + O_HB);

  __shared__ __align__(16) u16 Et[8][1024];   // wave-private [16][64] bf16, slot-swizzled
  u16* myT = Et[wave];
  u32* myT32 = (u32*)myT;

#pragma unroll 1
  for (int p=0;p<2;p++){
    const void* src = p ? obs : ext;
    void* dst = p ? ax_out : rnn_in;
    const int h1 = p?HX1:HU1, h2 = p?HX2:HU2, h3 = p?HW3X:HW3U;
    const int b1o = p?O_PXB1:O_PUB1, b2o = p?O_PXB2:O_PUB2, b3o = p?O_AB1:O_RNB;

    // ---- weight fragments ----
    bf16x8 w1[4], w2[4][2], w3[4][2];
    float bb1[4], bb2[4], bb3[4];
#pragma unroll
    for (int n=0;n<4;n++){
      const int j = n*16 + lr;
      w1[n] = (lg<2) ? load16(Wh + h1 + j*16 + lg*8) : zfrag();
#pragma unroll
      for (int kk=0;kk<2;kk++){
        w2[n][kk] = load16(Wh + h2 + j*64 + kk*32 + lg*8);
        w3[n][kk] = load16(Wh + h3 + j*64 + kk*32 + lg*8);
      }
      bb1[n] = W[b1o+j]; bb2[n] = W[b2o+j]; bb3[n] = W[b3o+j];
    }

#pragma unroll 1
    for (int it=0; it<K1_NT; ++it){
      const size_t row0 = ((size_t)(blockIdx.x*8 + wave)*K1_NT + it)*16;

      // ---- input A-frag (K=16 padded to 32) ----
      bf16x8 xa;
      if (lg < 2){
        if constexpr (MODE){
          const float4* sp = (const float4*)((const float*)src + (row0+lr)*16);
          float4 f0 = sp[lg*2], f1 = sp[lg*2+1];
          union { short s[8]; bf16x8 v; } c;
          c.s[0]=(short)f2b(f0.x); c.s[1]=(short)f2b(f0.y);
          c.s[2]=(short)f2b(f0.z); c.s[3]=(short)f2b(f0.w);
          c.s[4]=(short)f2b(f1.x); c.s[5]=(short)f2b(f1.y);
          c.s[6]=(short)f2b(f1.z); c.s[7]=(short)f2b(f1.w);
          xa = c.v;
        } else {
          xa = load16((const u16*)src + (row0+lr)*16 + lg*8);
        }
      } else xa = zfrag();

      // ---- L1 ----
      f32x4 c[4];
#pragma unroll
      for (int n=0;n<4;n++){
        f32x4 ci = {bb1[n],bb1[n],bb1[n],bb1[n]};
        ci = mfma16(xa, w1[n], ci);
#pragma unroll
        for (int r=0;r<4;r++){
          float v = fmaxf(ci[r], 0.0f);
          const int b = lg*4 + r, j = n*16 + lr;
          myT[b*64 + (((j>>3)^(b&7))<<3) + (j&7)] = f2b(v);
        }
      }
      // ---- L2 ----
      {
        bf16x8 a0 = ldA64(myT32, lr, lg);
        bf16x8 a1 = ldA64(myT32, lr, 4+lg);
#pragma unroll
        for (int n=0;n<4;n++){
          f32x4 ci = {bb2[n],bb2[n],bb2[n],bb2[n]};
          ci = mfma16(a0, w2[n][0], ci);
          ci = mfma16(a1, w2[n][1], ci);
          c[n] = ci;
        }
#pragma unroll
        for (int n=0;n<4;n++)
#pragma unroll
          for (int r=0;r<4;r++){
            float v = fmaxf(c[n][r], 0.0f);
            const int b = lg*4 + r, j = n*16 + lr;
            myT[b*64 + (((j>>3)^(b&7))<<3) + (j&7)] = f2b(v);
          }
      }
      // ---- L3 (linear) ----
      {
        bf16x8 a0 = ldA64(myT32, lr, lg);
        bf16x8 a1 = ldA64(myT32, lr, 4+lg);
#pragma unroll
        for (int n=0;n<4;n++){
          f32x4 ci = {bb3[n],bb3[n],bb3[n],bb3[n]};
          ci = mfma16(a0, w3[n][0], ci);
          ci = mfma16(a1, w3[n][1], ci);
          c[n] = ci;
        }
#pragma unroll
        for (int n=0;n<4;n++)
#pragma unroll
          for (int r=0;r<4;r++){
            const int b = lg*4 + r, j = n*16 + lr;
            myT[b*64 + (((j>>3)^(b&7))<<3) + (j&7)] = f2b(c[n][r]);
          }
      }
      // ---- coalesced store: 2 slots per lane ----
#pragma unroll
      for (int s2=0;s2<2;s2++){
        const int s_lin = lane*2 + s2;
        const int r = s_lin>>3, sl = s_lin&7;
        uint4 v = ((const uint4*)myT32)[r*8 + (sl^(r&7))];
        if constexpr (MODE){
          float* dp = (float*)dst + (row0+r)*64 + sl*8;
          u32 w[4] = {v.x, v.y, v.z, v.w};
          float f[8];
#pragma unroll
          for (int i=0;i<4;i++){ f[2*i] = b2f((u16)(w[i]&0xffffu)); f[2*i+1] = b2f((u16)(w[i]>>16)); }
          ((float4*)dp)[0] = make_float4(f[0],f[1],f[2],f[3]);
          ((float4*)dp)[1] = make_float4(f[4],f[5],f[6],f[7]);
        } else {
          ((uint4*)((u16*)dst + (row0+r)*64))[sl] = v;
        }
      }
    }
  }
}

// 16-term partial dot with 2 accumulator chains
__device__ __forceinline__ float dot16(const float* w, float4 a, float4 b, float4 c, float4 d){
  float s0=0.f, s1=0.f;
  s0=fmaf(w[0],a.x,s0);  s1=fmaf(w[1],a.y,s1);  s0=fmaf(w[2],a.z,s0);  s1=fmaf(w[3],a.w,s1);
  s0=fmaf(w[4],b.x,s0);  s1=fmaf(w[5],b.y,s1);  s0=fmaf(w[6],b.z,s0);  s1=fmaf(w[7],b.w,s1);
  s0=fmaf(w[8],c.x,s0);  s1=fmaf(w[9],c.y,s1);  s0=fmaf(w[10],c.z,s0); s1=fmaf(w[11],c.w,s1);
  s0=fmaf(w[12],d.x,s0); s1=fmaf(w[13],d.y,s1); s0=fmaf(w[14],d.z,s0); s1=fmaf(w[15],d.w,s1);
  return s0+s1;
}

// -------------------- K2: sequential RNN + a-layer (WG per batch lane) --------------------
// r4 structure + lgkm-only barriers + register prefetch of rnn_in/ax one step ahead
template<int MODE>
__global__ __launch_bounds__(256) void k2_rnn(
  const float* __restrict__ W, void* __restrict__ outb)
{
  if (!live(W, MODE ? 2 : 1)) return;
  void* a_seq  = chunkp<MODE>(outb, 0);
  void* rnn_in = chunkp<MODE>(outb, 1);
  void* ax     = chunkp<MODE>(outb, 2);
  void* d_seq  = chunkp<MODE>(outb, 3);

  const int b = blockIdx.x;
  const int tid = threadIdx.x;
  const int q = tid>>6, j = tid&63;

  float wh[16], wa1[16], wa2[16];
#pragma unroll
  for (int i=0;i<16;i++){
    wh[i]  = W[O_WHH + j*64  + q*16 + i];
    wa1[i] = W[O_AW1 + j*128 + q*16 + i];   // d-half (cols 0..63)
    wa2[i] = W[O_AW2 + j*64  + q*16 + i];
  }
  const float ab2j = W[O_AB2 + j];

  __shared__ __align__(16) float h_lds[64];
  __shared__ __align__(16) float v_lds[64];
  __shared__ __align__(16) float red1[256], red2[256], red3[256];
  if (tid < 64){ h_lds[tid] = 0.f; v_lds[tid] = 0.f; }

  const size_t brow = (size_t)b*64 + j;
  float pre = 0.f;
  if (q==0) pre = ldOne<MODE>(rnn_in, brow);   // rnn_in[t=0]
  __syncthreads();

  for (int t=0; t<L+2; ++t){
    const float4* hv = (const float4*)(&h_lds[q*16]);
    const float4* vv = (const float4*)(&v_lds[q*16]);
    float4 h0=hv[0], h1=hv[1], h2=hv[2], h3=hv[3];
    float4 v0=vv[0], v1=vv[1], v2=vv[2], v3=vv[3];
    red1[tid] = dot16(wh,  h0,h1,h2,h3);
    red2[tid] = dot16(wa1, h0,h1,h2,h3);
    red3[tid] = dot16(wa2, v0,v1,v2,v3);
    bar_lds();
    if (q==0){
      if (t < L){
        const size_t idx = (size_t)t*(BB*64) + brow;
        float s = red1[j]+red1[64+j]+red1[128+j]+red1[192+j] + pre;
        float hn = tanhf_fast(s);
        h_lds[j] = hn;
        stOne<MODE>(d_seq, idx, hn);
      }
      if (t+1 < L) pre = ldOne<MODE>(rnn_in, (size_t)(t+1)*(BB*64) + brow);
    } else if (q==1){
      if (t>=1 && t<=L){
        const size_t idx = (size_t)(t-1)*(BB*64) + brow;
        float s = red2[j]+red2[64+j]+red2[128+j]+red2[192+j] + pre;
        v_lds[j] = tanhf_fast(s);
      }
      if (t < L) pre = ldOne<MODE>(ax, (size_t)t*(BB*64) + brow);  // used at t+1
    } else if (q==2){
      if (t>=2){
        const size_t idx = (size_t)(t-2)*(BB*64) + brow;
        float s = red3[j]+red3[64+j]+red3[128+j]+red3[192+j] + ab2j;
        stOne<MODE>(a_seq, idx, s);
      }
    }
    bar_lds();
  }
}

// -------------------- K4M: MFMA latent scan (WG per 16 batch lanes) --------------------
// r4 known-good structure + lgkm-only barriers + DEPTH-2 prefetch:
// pf_issue(t+2) immediately after pf_write(t+1) in phase B -> each load has a
// full step (~3000 cy) in flight instead of only stage A.
template<int MODE>
__global__ __launch_bounds__(512,2) void k4m(
  const float* __restrict__ W,
  const void* __restrict__ noise, void* __restrict__ outb)
{
  if (!live(W, MODE ? 2 : 1)) return;
  void* amu = chunkp<MODE>(outb, 0);   // reads a_seq, writes state_mu
  void* lsc = chunkp<MODE>(outb, 1);   // writes state_logsigma
  void* zc  = chunkp<MODE>(outb, 2);   // writes sampled_state
  void* dsq = chunkp<MODE>(outb, 3);   // reads d_seq

  const int G = blockIdx.x;
  const int tid = threadIdx.x;
  const int wave = tid>>6, lane = tid&63;
  const int lr = lane&15, lg = lane>>4;

  __shared__ __align__(16) u32 Zbuf[512];          // [16][64] bf16, 16B-slot swizzled
  __shared__ __align__(16) u32 Abuf[2][512];       // a_t   (same layout)
  __shared__ __align__(16) u32 Dbuf[2][512];       // d_t
  __shared__ __align__(16) u32 Ebuf[2][1024];      // eps as f32 bits, [16][64] plain
  __shared__ __align__(16) u32 Tpo[1024];          // t_po [16][128] bf16 swizzled
  __shared__ __align__(16) u32 Tpr[1024];
  __shared__ __align__(16) float Obuf[3*1024];     // po_mu/po_ls/pr_mu outs, [16][64] f32, slot-swizzled by b
  __shared__ float bmu[64], bls[64];

  const bool isPo = wave < 4;
  const int wq = wave & 3;
  const int jA = wq*32;

  // ---- stage-A weight fragments (all 8 waves) ----
  const int of1 = isPo ? O_POF1 : O_PRF1;
  const int of2 = isPo ? O_POF2 : O_PRF2;
  bf16x8 wf1[2][4], wf2[2][4];
  float bA1[2], bA2[2];
#pragma unroll
  for (int nt=0; nt<2; ++nt){
    const int j = jA + nt*16 + lr;
    bA1[nt] = W[(isPo?O_POF1B:O_PRF1B) + j];
    bA2[nt] = W[(isPo?O_POF2B:O_PRF2B) + j];
#pragma unroll
    for (int kk=0; kk<4; ++kk){
      const int k = kk*32 + lg*8;
      wf1[nt][kk] = wfrag(W, of1 + j*128 + k);
      wf2[nt][kk] = wfrag(W, of2 + j*128 + k);
    }
  }
  // ---- stage-B weight fragments (waves 0..5) ----
  const int mb = wave>>1, nh = wave&1;
  bf16x8 wb[2][4];
  if (wave < 6){
    const int ob = (mb==0) ? O_POMU : (mb==1 ? O_POLS : O_PRMU);
#pragma unroll
    for (int nt=0; nt<2; ++nt)
#pragma unroll
      for (int kk=0; kk<4; ++kk){
        const int j = nh*32 + nt*16 + lr;
        const int k = kk*32 + lg*8;
        wb[nt][kk] = wfrag(W, ob + j*128 + k);
      }
  }

  // ---- init: biases, zero z, initial prefetch ----
  if (tid < 64){ bmu[tid] = W[O_POMUB+tid] + W[O_PRMUB+tid]; bls[tid] = W[O_POLSB+tid]; }
  Zbuf[tid & 511] = 0;

  const int pr_ = lane>>2, pc = lane&3;      // prefetch row / col-group
  float4 pA[4], pE[4]; uint4 qA[2], qE[2];

  auto pf_issue = [&](int tt){
    const size_t rowb = ((size_t)tt*BB + G*16 + pr_)*64;
    const void* gsrc = (wave==6) ? amu : dsq;
    if constexpr (MODE){
      const float4* sp = (const float4*)((const float*)gsrc + rowb) + pc*4;
#pragma unroll
      for (int i=0;i<4;i++) pA[i] = sp[i];
      if (wave==6){
        const float4* ep = (const float4*)((const float*)noise + rowb) + pc*4;
#pragma unroll
        for (int i=0;i<4;i++) pE[i] = ep[i];
      }
    } else {
      const uint4* sp = (const uint4*)((const u16*)gsrc + rowb) + pc*2;
      qA[0] = sp[0]; qA[1] = sp[1];
      if (wave==6){
        const uint4* ep = (const uint4*)((const u16*)noise + rowb) + pc*2;
        qE[0] = ep[0]; qE[1] = ep[1];
      }
    }
  };
  auto pf_write = [&](int buf){
    u32* dst = (wave==6) ? Abuf[buf] : Dbuf[buf];
    uint4* d0 = (uint4*)dst + (pr_*8 + ((pc*2  ) ^ (pr_&7)));
    uint4* d1 = (uint4*)dst + (pr_*8 + ((pc*2+1) ^ (pr_&7)));
    if constexpr (MODE){
      u32 w[8];
#pragma unroll
      for (int i=0;i<4;i++){
        w[2*i]   = (u32)f2b(pA[i].x) | ((u32)f2b(pA[i].y)<<16);
        w[2*i+1] = (u32)f2b(pA[i].z) | ((u32)f2b(pA[i].w)<<16);
      }
      *d0 = make_uint4(w[0],w[1],w[2],w[3]);
      *d1 = make_uint4(w[4],w[5],w[6],w[7]);
      if (wave==6){
        uint4* eb = (uint4*)Ebuf[buf] + (pr_*16 + pc*4);
#pragma unroll
        for (int i=0;i<4;i++){
          union { float4 f; uint4 u; } cv; cv.f = pE[i];
          eb[i] = cv.u;
        }
      }
    } else {
      *d0 = qA[0]; *d1 = qA[1];
      if (wave==6){
        u32* Eb = Ebuf[buf] + pr_*64 + pc*16;
        u32 ww[4] = {qE[0].x, qE[0].y, qE[0].z, qE[0].w};
#pragma unroll
        for (int i=0;i<4;i++){ Eb[2*i] = ww[i]<<16; Eb[2*i+1] = ww[i] & 0xffff0000u; }
        u32 w2[4] = {qE[1].x, qE[1].y, qE[1].z, qE[1].w};
#pragma unroll
        for (int i=0;i<4;i++){ Eb[8+2*i] = w2[i]<<16; Eb[8+2*i+1] = w2[i] & 0xffff0000u; }
      }
    }
  };

  if (wave >= 6){
    pf_issue(0); pf_write(0);     // step 0 resident
    if (L > 1) pf_issue(1);       // step 1 in flight (full step ahead)
  }
  __syncthreads();

  for (int t=0; t<L; ++t){
    const int cur = t&1, nb = cur^1;

    // ---- stage A: all 8 waves, 16 MFMA each ----
    const u32* ADc = isPo ? Abuf[cur] : Dbuf[cur];
    bf16x8 a0 = ldA64(Zbuf, lr, lg);
    bf16x8 a1 = ldA64(Zbuf, lr, 4+lg);
    bf16x8 a2 = ldA64(ADc,  lr, lg);
    bf16x8 a3 = ldA64(ADc,  lr, 4+lg);
    f32x4 c1[2], c2[2];
#pragma unroll
    for (int nt=0; nt<2; ++nt){
      f32x4 i1 = {bA1[nt],bA1[nt],bA1[nt],bA1[nt]};
      f32x4 i2 = {bA2[nt],bA2[nt],bA2[nt],bA2[nt]};
      i1 = mfma16(a0, wf1[nt][0], i1);
      i1 = mfma16(a1, wf1[nt][1], i1);
      i1 = mfma16(a2, wf1[nt][2], i1);
      i1 = mfma16(a3, wf1[nt][3], i1);
      i2 = mfma16(a0, wf2[nt][0], i2);
      i2 = mfma16(a1, wf2[nt][1], i2);
      i2 = mfma16(a2, wf2[nt][2], i2);
      i2 = mfma16(a3, wf2[nt][3], i2);
      c1[nt] = i1; c2[nt] = i2;
    }
    // t = tanh(fc1)*sigm(fc2), write bf16 into T (A-operand layout, swizzled)
    u16* Td = (u16*)(isPo ? Tpo : Tpr);
#pragma unroll
    for (int nt=0; nt<2; ++nt)
#pragma unroll
      for (int r=0; r<4; ++r){
        float tv = tanhf_fast(c1[nt][r]) * sigm_fast(c2[nt][r]);
        const int j = jA + nt*16 + lr;
        const int b = lg*4 + r;
        Td[b*128 + (((j>>3)^(b&7))<<3) + (j&7)] = f2b(tv);
      }
    bar_lds();  // S2: T ready

    // ---- stage B: waves 0..5 output matmuls; waves 6,7 write t+1 + issue t+2 ----
    if (wave < 6){
      const u32* Ts = (mb==2) ? Tpr : Tpo;
      bf16x8 t0 = ldT(Ts, lr, lg);
      bf16x8 t1 = ldT(Ts, lr, 4+lg);
      bf16x8 t2 = ldT(Ts, lr, 8+lg);
      bf16x8 t3 = ldT(Ts, lr, 12+lg);
      f32x4 d0 = {0.f,0.f,0.f,0.f}, d1 = {0.f,0.f,0.f,0.f};
      d0 = mfma16(t0, wb[0][0], d0);
      d0 = mfma16(t1, wb[0][1], d0);
      d0 = mfma16(t2, wb[0][2], d0);
      d0 = mfma16(t3, wb[0][3], d0);
      d1 = mfma16(t0, wb[1][0], d1);
      d1 = mfma16(t1, wb[1][1], d1);
      d1 = mfma16(t2, wb[1][2], d1);
      d1 = mfma16(t3, wb[1][3], d1);
      float* Od = &Obuf[mb*1024];
#pragma unroll
      for (int r=0; r<4; ++r){
        const int b = lg*4 + r;
        const int j0 = nh*32 + lr;
        const int j1 = nh*32 + 16 + lr;
        Od[b*64 + (((j0>>2)^(b&7))<<2) + (j0&3)] = d0[r];
        Od[b*64 + (((j1>>2)^(b&7))<<2) + (j1&3)] = d1[r];
      }
    } else if (t+1 < L){
      pf_write(nb);                 // data issued a full step ago
      if (t+2 < L) pf_issue(t+2);   // next load: in flight across the whole next step
    }
    bar_lds();  // S3: outs + next a/d/eps ready

    // ---- z update: 512 threads cover 16x64, 2 outputs each ----
    {
      const int b = tid>>5;
      const int j = (tid&31)*2;
      const int sidx = b*64 + (((j>>2)^(b&7))<<2) + (j&3);
      float2 vpo = *(const float2*)&Obuf[0*1024 + sidx];
      float2 vls = *(const float2*)&Obuf[1*1024 + sidx];
      float2 vpr = *(const float2*)&Obuf[2*1024 + sidx];
      float2 bm = *(const float2*)&bmu[j];
      float2 bl = *(const float2*)&bls[j];
      float e0 = __uint_as_float(Ebuf[cur][b*64 + j]);
      float e1 = __uint_as_float(Ebuf[cur][b*64 + j + 1]);
      float mu0 = vpo.x + vpr.x + bm.x;
      float mu1 = vpo.y + vpr.y + bm.y;
      float ls0 = vls.x + bl.x;
      float ls1 = vls.y + bl.y;
      float z0 = fmaf(EXP2(ls0*0.7213475204444817f), e0, mu0);
      float z1 = fmaf(EXP2(ls1*0.7213475204444817f), e1, mu1);
      // write z into Zbuf (bf16 pair, swizzled slot)
      Zbuf[b*32 + (((j>>3)^(b&7))<<2) + ((j&7)>>1)] = (u32)f2b(z0) | ((u32)f2b(z1)<<16);
      // global outputs
      const size_t idx = ((size_t)t*BB + G*16 + b)*64 + j;
      if constexpr (MODE){
        *(float2*)((float*)amu + idx) = make_float2(mu0, mu1);
        *(float2*)((float*)lsc + idx) = make_float2(ls0, ls1);
        *(float2*)((float*)zc  + idx) = make_float2(z0, z1);
      } else {
        *(u32*)((u16*)amu + idx) = (u32)f2b(mu0) | ((u32)f2b(mu1)<<16);
        *(u32*)((u16*)lsc + idx) = (u32)f2b(ls0) | ((u32)f2b(ls1)<<16);
        *(u32*)((u16*)zc  + idx) = (u32)f2b(z0)  | ((u32)f2b(z1)<<16);
      }
    }
    bar_lds();  // S4: z ready for next step
  }
}

extern "C" void kernel_launch(void* const* d_in, const int* in_sizes, int n_in,
                              void* d_out, int out_size, void* d_ws, size_t ws_size,
                              hipStream_t stream)
{
  (void)in_sizes; (void)n_in; (void)out_size; (void)ws_size;

  const void* ext   = d_in[0];
  const void* obs   = d_in[1];
  const void* noise = d_in[2];
  float* W = (float*)d_ws;

  kprobe<<<1,64,0,stream>>>((const u32*)ext, (u32*)W + O_FLAG);

#define K0ARGS \
    d_in[3],  d_in[4],  d_in[5],  d_in[6],  d_in[7],  d_in[8],  d_in[9],  d_in[10], \
    d_in[11], d_in[12], d_in[13], d_in[14], d_in[15], d_in[16], d_in[17], d_in[18], \
    d_in[19], d_in[20], d_in[21], d_in[22], d_in[23], d_in[24], d_in[25], d_in[26], \
    d_in[27], d_in[28], d_in[29], d_in[30], d_in[31], d_in[32], W

  k0_convert<0><<<64,256,0,stream>>>(K0ARGS);
  k0_convert<1><<<64,256,0,stream>>>(K0ARGS);
#undef K0ARGS

  k1m<0><<<NROWS/(8*K1_NT*16), 512, 0, stream>>>(ext, obs, W, d_out);
  k1m<1><<<NROWS/(8*K1_NT*16), 512, 0, stream>>>(ext, obs, W, d_out);

  k2_rnn<0><<<BB, 256, 0, stream>>>(W, d_out);
  k2_rnn<1><<<BB, 256, 0, stream>>>(W, d_out);

  k4m<0><<<32, 512, 0, stream>>>(W, noise, d_out);
  k4m<1><<<32, 512, 0, stream>>>(W, noise, d_out);
}